// Round 7
// baseline (197.811 us; speedup 1.0000x reference)
//
#include <hip/hip_runtime.h>
#include <hip/hip_bf16.h>

#define DIM   512
#define NSEQ  1024
#define NB    8
#define NH    8
#define HD    64
#define NTOK  8192   // NB*NSEQ

typedef __attribute__((ext_vector_type(8))) short  short8;
typedef __attribute__((ext_vector_type(4))) short  short4v;
typedef __attribute__((ext_vector_type(4))) float  floatx4;
typedef __attribute__((ext_vector_type(4))) int    intx4;
typedef __attribute__((ext_vector_type(2))) int    intx2;
typedef __attribute__((ext_vector_type(8))) __bf16 bf16x8;

__device__ inline short f2bf(float x) {
    union { float f; unsigned u; } c; c.f = x;
    unsigned r = c.u + 0x7fffu + ((c.u >> 16) & 1u);
    return (short)(r >> 16);
}
__device__ inline float bf2f(short s) {
    union { unsigned u; float f; } c; c.u = ((unsigned)(unsigned short)s) << 16;
    return c.f;
}
// truncate-pack two fp32 -> two bf16 in one v_perm (used ONLY for attn P, where the
// softmax weights tolerate 1-ulp downward bias; R6 post-mortem: do NOT use for GEMM inputs)
__device__ inline unsigned pkbf(float hi, float lo) {
    return __builtin_amdgcn_perm(
        __builtin_bit_cast(unsigned, hi), __builtin_bit_cast(unsigned, lo), 0x07060302u);
}
// round-to-nearest-even pack: 2 fp32 -> 2 bf16 (3 VALU/elem + 1 perm; staging-phase only)
__device__ inline unsigned pkbf_rn(float hi, float lo) {
    unsigned uh = __builtin_bit_cast(unsigned, hi);
    unsigned ul = __builtin_bit_cast(unsigned, lo);
    uh += 0x7fffu + ((uh >> 16) & 1u);
    ul += 0x7fffu + ((ul >> 16) & 1u);
    return __builtin_amdgcn_perm(uh, ul, 0x07060302u);
}
// pack 8 fp32 (two float4) -> short8 of bf16, round-to-nearest (R6 fix: truncation here
// cost a full bf16 ulp of output margin; rounding restores R4's absmax)
__device__ inline short8 pk8(float4 a, float4 b) {
    intx4 pk;
    pk.x = (int)pkbf_rn(a.y, a.x);
    pk.y = (int)pkbf_rn(a.w, a.z);
    pk.z = (int)pkbf_rn(b.y, b.x);
    pk.w = (int)pkbf_rn(b.w, b.z);
    return __builtin_bit_cast(short8, pk);
}
__device__ inline floatx4 mfma16(short8 a, short8 b, floatx4 c) {
    return __builtin_amdgcn_mfma_f32_16x16x32_bf16(
        __builtin_bit_cast(bf16x8, a), __builtin_bit_cast(bf16x8, b), c, 0, 0, 0);
}
__device__ inline floatx4 mfma_pv(short4v a, short4v b, floatx4 c) {
#if __has_builtin(__builtin_amdgcn_mfma_f32_16x16x16bf16_1k)
    return __builtin_amdgcn_mfma_f32_16x16x16bf16_1k(a, b, c, 0, 0, 0);
#else
    asm("v_mfma_f32_16x16x16_bf16 %0, %1, %2, %0" : "+v"(c) : "v"(a), "v"(b));
    return c;
#endif
}
__device__ inline void gld_lds16(const void* g, void* l) {
    __builtin_amdgcn_global_load_lds(
        (__attribute__((address_space(1))) void*)(g),
        (__attribute__((address_space(3))) void*)(l), 16, 0, 0);
}

// ---------------- prep: tiled W transpose only (256 blocks) ----------------
__global__ __launch_bounds__(256) void prep_kernel(
        const float* __restrict__ Wq, const float* __restrict__ Wk,
        const float* __restrict__ Wv, const float* __restrict__ Wo,
        short* __restrict__ WqT, short* __restrict__ WkT,
        short* __restrict__ WvT, short* __restrict__ WoT) {
    const int tid = threadIdx.x;
    __shared__ short Ts[64 * 65];
    const int b = blockIdx.x;
    const int wsel = b >> 6, tile = b & 63;
    const int tr = (tile >> 3) * 64;                // k base
    const int tc = (tile & 7) * 64;                 // n base
    const float* src = (wsel == 0) ? Wq : (wsel == 1) ? Wk : (wsel == 2) ? Wv : Wo;
    short* dst       = (wsel == 0) ? WqT : (wsel == 1) ? WkT : (wsel == 2) ? WvT : WoT;
#pragma unroll
    for (int i = 0; i < 16; i++) {
        const int idx = i * 256 + tid;              // over 64x64
        const int r = idx >> 6, c = idx & 63;       // coalesced read
        Ts[c * 65 + r] = f2bf(src[(size_t)(tr + r) * 512 + tc + c]);
    }
    __syncthreads();
#pragma unroll
    for (int i = 0; i < 16; i++) {
        const int idx = i * 256 + tid;
        const int n = idx >> 6, k = idx & 63;       // coalesced write
        dst[(size_t)(tc + n) * 512 + tr + k] = Ts[n * 65 + k];
    }
}

// ---------------- fused QKV projection GEMM: T14 reg-staged, fp32-A cast fused ---------------
// grid (64, 12): x = m-block, y: sel = y>>2 {0:Q->Qpb, 1:K->Kpb, 2:K->Vt}.
__global__ __launch_bounds__(256) void proj_kernel(
        const float* __restrict__ Qf, const float* __restrict__ Kf,
        const short* __restrict__ WqT, const short* __restrict__ WkT,
        const short* __restrict__ WvT,
        const float* __restrict__ bq, const float* __restrict__ bk,
        const float* __restrict__ bv,
        short* __restrict__ Qpb, short* __restrict__ Kpb,
        short* __restrict__ Vt) {
    __shared__ __attribute__((aligned(16))) char smem[36864]; // As 16K + Bs 16K; epilogue aliases
    short* As = (short*)smem;                 // 128 x 64 bf16
    short* Bs = (short*)(smem + 16384);       // 128 x 64 bf16
    const int tid = threadIdx.x;
    const int w = tid >> 6, ln = tid & 63;
    const int quad = ln >> 4, col = ln & 15;
    const int nb = blockIdx.y;
    const int sel = nb >> 2;
    const int n0 = (nb & 3) * 128;
    const int m0 = blockIdx.x * 128;
    const int wr = w >> 1, wc = w & 1;
    const float* Af   = (sel == 0) ? Qf : Kf;
    const short* BT   = (sel == 0) ? WqT : (sel == 1) ? WkT : WvT;
    const float* bias = (sel == 0) ? bq : (sel == 1) ? bk : bv;

    floatx4 acc[4][4];
#pragma unroll
    for (int i = 0; i < 4; i++)
#pragma unroll
        for (int j = 0; j < 4; j++) acc[i][j] = (floatx4)0.0f;

    // per-thread staging slots: slot = i*256+tid -> r = slot>>3, c = (slot&7)^(r&7)
    const float* Ag[4]; const short* Bg[4]; int lof[4];
#pragma unroll
    for (int i = 0; i < 4; i++) {
        const int slot = i * 256 + tid;
        const int r = slot >> 3;
        const int c = (slot & 7) ^ (r & 7);
        Ag[i] = Af + (size_t)(m0 + r) * 512 + c * 8;   // fp32, 32B per chunk
        Bg[i] = BT + (size_t)(n0 + r) * 512 + c * 8;   // bf16, 16B per chunk
        lof[i] = slot * 8;
    }

    float4 raf[4][2]; short8 rbv[4];
#pragma unroll
    for (int i = 0; i < 4; i++) {
        raf[i][0] = *(const float4*)(Ag[i]);
        raf[i][1] = *(const float4*)(Ag[i] + 4);
        rbv[i]    = *(const short8*)(Bg[i]);
    }
#pragma unroll
    for (int i = 0; i < 4; i++) {
        *(short8*)&As[lof[i]] = pk8(raf[i][0], raf[i][1]);
        *(short8*)&Bs[lof[i]] = rbv[i];
    }
    __syncthreads();

    for (int t = 0; t < 8; t++) {
        if (t < 7) {
            const int kk = (t + 1) * 64;
#pragma unroll
            for (int i = 0; i < 4; i++) {
                raf[i][0] = *(const float4*)(Ag[i] + kk);
                raf[i][1] = *(const float4*)(Ag[i] + kk + 4);
                rbv[i]    = *(const short8*)(Bg[i] + kk);
            }
        }
#pragma unroll
        for (int s = 0; s < 2; s++) {
            short8 af[4], bfr[4];
#pragma unroll
            for (int i = 0; i < 4; i++) {
                const int row = wr * 64 + i * 16 + col;
                const int cs = (s * 4 + quad) ^ (col & 7);
                af[i] = *(const short8*)&As[row * 64 + cs * 8];
            }
#pragma unroll
            for (int j = 0; j < 4; j++) {
                const int row = wc * 64 + j * 16 + col;
                const int cs = (s * 4 + quad) ^ (col & 7);
                bfr[j] = *(const short8*)&Bs[row * 64 + cs * 8];
            }
#pragma unroll
            for (int i = 0; i < 4; i++)
#pragma unroll
                for (int j = 0; j < 4; j++)
                    acc[i][j] = mfma16(af[i], bfr[j], acc[i][j]);
        }
        __syncthreads();                 // all waves done reading the buffer
        if (t < 7) {
#pragma unroll
            for (int i = 0; i < 4; i++) {
                *(short8*)&As[lof[i]] = pk8(raf[i][0], raf[i][1]); // vmcnt wait lands here
                *(short8*)&Bs[lof[i]] = rbv[i];
            }
        }
        __syncthreads();                 // buffer ready for next step
    }

    if (sel < 2) {
        // coalesced epilogue: wave-private LDS tile (64x72 shorts, +8 pad), then 16B row stores
        short* Es = (short*)smem + w * (64 * 72);
        short* C = (sel == 0) ? Qpb : Kpb;
#pragma unroll
        for (int j = 0; j < 4; j++) {
            const float bj = bias[n0 + wc * 64 + j * 16 + col];
#pragma unroll
            for (int i = 0; i < 4; i++)
#pragma unroll
                for (int r = 0; r < 4; r++)
                    Es[(i * 16 + quad * 4 + r) * 72 + j * 16 + col] = f2bf(acc[i][j][r] + bj);
        }
        // wave-private region: intra-wave LDS RAW ordering suffices, no barrier
        const int lr = ln >> 3, lc = (ln & 7) * 8;
#pragma unroll
        for (int u = 0; u < 8; u++) {
            const short8 v = *(const short8*)&Es[(u * 8 + lr) * 72 + lc];
            *(short8*)(C + (size_t)(m0 + wr * 64 + u * 8 + lr) * 512 + n0 + wc * 64 + lc) = v;
        }
    } else {
        // transposed epilogue: Vt[dv][tok], two 64-col halves through LDS (cross-wave -> barriers)
        short* Ts = (short*)smem;                    // 64 x 136 = 17408 B
        const int dvl = tid >> 2;
        const int tch = (tid & 3) * 32;
#pragma unroll
        for (int hc = 0; hc < 2; hc++) {
            __syncthreads();
            if (wc == hc) {
#pragma unroll
                for (int j = 0; j < 4; j++) {
                    const float bj = bias[n0 + hc * 64 + j * 16 + col];
#pragma unroll
                    for (int i = 0; i < 4; i++)
#pragma unroll
                        for (int r = 0; r < 4; r++)
                            Ts[(j * 16 + col) * 136 + wr * 64 + i * 16 + quad * 4 + r] =
                                f2bf(acc[i][j][r] + bj);
                }
            }
            __syncthreads();
#pragma unroll
            for (int u = 0; u < 4; u++)
                *(intx4*)(Vt + (size_t)(n0 + hc * 64 + dvl) * NTOK + m0 + tch + u * 8) =
                    *(const intx4*)&Ts[dvl * 136 + tch + u * 8];
        }
    }
}

// ---------------- fused flash attention + residual (R9 structure) ----------------
__global__ __launch_bounds__(512) void attn_kernel(
        const short* __restrict__ Qp, const short* __restrict__ Kp,
        const short* __restrict__ Vt, short* __restrict__ Xo) {
    __shared__ __attribute__((aligned(16))) short Ks[2][128 * 64];
    __shared__ __attribute__((aligned(16))) short Vs[2][64 * 128];
    const int tid = threadIdx.x;
    const int w = tid >> 6, ln = tid & 63;
    const int quad = ln >> 4, col = ln & 15;
    const int gid = blockIdx.x;
    const int h = gid & 7;                  // XCD pin: one head per XCD
    const int rest = gid >> 3;              // 0..63
    const int b = rest >> 3;                // 0..7
    const int qt = rest & 7;                // 0..7
    const int q0 = qt * 128 + w * 16;
    const size_t baseQ = (size_t)b * NSEQ * DIM + (size_t)h * HD;
    const size_t baseV = (size_t)h * HD * NTOK + (size_t)b * NSEQ;
    const float sc = 1.44269504089f / 22.6274169979f;   // log2e / sqrt(512)

    const int ks0 = tid, ks1 = 512 + tid;
    const int kr0 = ks0 >> 3, kc0 = (ks0 & 7) ^ (kr0 & 7);
    const int kr1 = ks1 >> 3, kc1 = (ks1 & 7) ^ (kr1 & 7);
    const int vr0 = ks0 >> 4, vc0 = (ks0 & 15) ^ (vr0 & 15);
    const int vr1 = ks1 >> 4, vc1 = (ks1 & 15) ^ (vr1 & 15);
    const short* kp0 = Kp + baseQ + (size_t)kr0 * DIM + kc0 * 8;
    const short* kp1 = Kp + baseQ + (size_t)kr1 * DIM + kc1 * 8;
    const short* vp0 = Vt + baseV + (size_t)vr0 * NTOK + vc0 * 8;
    const short* vp1 = Vt + baseV + (size_t)vr1 * NTOK + vc1 * 8;
    const int ldsl0 = (w * 64) * 8;
    const int ldsl1 = (512 + w * 64) * 8;

    short8 qa[2];
#pragma unroll
    for (int s = 0; s < 2; s++) {
        short8 raw = *(const short8*)(Qp + baseQ + (size_t)(q0 + col) * DIM + s * 32 + quad * 8);
        short8 sq;
#pragma unroll
        for (int j = 0; j < 8; j++) sq[j] = f2bf(bf2f(raw[j]) * sc);
        qa[s] = sq;
    }

    floatx4 oacc[4];
#pragma unroll
    for (int dt = 0; dt < 4; dt++) oacc[dt] = (floatx4)0.0f;
    float lp = 0.0f;

    gld_lds16(kp0, &Ks[0][ldsl0]);
    gld_lds16(kp1, &Ks[0][ldsl1]);
    gld_lds16(vp0, &Vs[0][ldsl0]);
    gld_lds16(vp1, &Vs[0][ldsl1]);
    __syncthreads();

    for (int t = 0; t < 8; t++) {
        const int cur = t & 1;
        if (t < 7) {
            const int kn = (t + 1) * 128;    // K advances by rows, V by cols
            const int nxt = cur ^ 1;
            gld_lds16(kp0 + (size_t)kn * DIM, &Ks[nxt][ldsl0]);
            gld_lds16(kp1 + (size_t)kn * DIM, &Ks[nxt][ldsl1]);
            gld_lds16(vp0 + kn, &Vs[nxt][ldsl0]);
            gld_lds16(vp1 + kn, &Vs[nxt][ldsl1]);
        }
        const short* Kc = Ks[cur];
        const short* Vc = Vs[cur];
#pragma unroll
        for (int nt = 0; nt < 8; nt++) {
            floatx4 z = (floatx4)0.0f;
#pragma unroll
            for (int s = 0; s < 2; s++) {
                const int cs = (s * 4 + quad) ^ (col & 7);
                const short8 kf = *(const short8*)&Kc[(nt * 16 + col) * 64 + cs * 8];
                z = mfma16(kf, qa[s], z);           // S^T tile
            }
            const float p0 = exp2f(z[0]), p1 = exp2f(z[1]);
            const float p2 = exp2f(z[2]), p3 = exp2f(z[3]);
            lp += (p0 + p1) + (p2 + p3);
            intx2 pd; pd.x = (int)pkbf(p1, p0); pd.y = (int)pkbf(p3, p2);
            const short4v pf = __builtin_bit_cast(short4v, pd);
#pragma unroll
            for (int dt = 0; dt < 4; dt++) {
                const int cs = (nt * 2 + (quad >> 1)) ^ col;
                const short4v vf = *(const short4v*)&Vc[(dt * 16 + col) * 128 + cs * 8 + (quad & 1) * 4];
                oacc[dt] = mfma_pv(pf, vf, oacc[dt]);
            }
        }
        __syncthreads();
    }

    lp += __shfl_xor(lp, 16);
    lp += __shfl_xor(lp, 32);
    float linv[4];
#pragma unroll
    for (int r = 0; r < 4; r++) linv[r] = 1.0f / __shfl(lp, quad * 4 + r);

#pragma unroll
    for (int dt = 0; dt < 4; dt++) {
#pragma unroll
        for (int r = 0; r < 4; r++) {
            const int q = q0 + quad * 4 + r;
            const size_t off = baseQ + (size_t)q * DIM + dt * 16 + col;
            Xo[off] = f2bf(oacc[dt][r] * linv[r] + bf2f(Qp[off]));
        }
    }
}

// ---------------- fused LN0 + out-proj GEMM + relu + residual + LN1, fp32 out ----------------
// grid 512 blocks x 512 threads; M=16 rows/block, full N=512 (2 blocks/CU, 16 waves/CU).
// Phase 1: LN0(Xat rows) -> bf16 A in LDS (chunk-XOR c^(row&7)); A never touches HBM.
// Phase 2: barrier-free k-loop; A from LDS, B per-lane from WoT (L2-resident).
// Phase 3: x = a + relu(acc+bo); per-row LN1 via per-wave partials in LDS; fp32 out.
__global__ __launch_bounds__(512) void gemm_final(
        const short* __restrict__ Xat, const short* __restrict__ WoT,
        const float* __restrict__ bo,
        const float* __restrict__ g0, const float* __restrict__ b0,
        const float* __restrict__ g1, const float* __restrict__ b1,
        float* __restrict__ out) {
    __shared__ __attribute__((aligned(16))) short As[16 * 512];      // 16 KB LN0'd A
    __shared__ float Ps[16][8][2];                                   // per-row per-wave partials
    __shared__ float Ms[16][2];                                      // mean, rstd per row
    const int tid = threadIdx.x;
    const int w = tid >> 6, ln = tid & 63;
    const int quad = ln >> 4, col = ln & 15;
    const int m0 = blockIdx.x * 16;

    // ---- phase 1: LN0 over this block's 16 rows (2 per wave) ----
    union { float4 f[2]; float v[8]; } g0v, b0v;
    g0v.f[0] = *(const float4*)(g0 + ln * 8); g0v.f[1] = *(const float4*)(g0 + ln * 8 + 4);
    b0v.f[0] = *(const float4*)(b0 + ln * 8); b0v.f[1] = *(const float4*)(b0 + ln * 8 + 4);
#pragma unroll
    for (int rr = 0; rr < 2; rr++) {
        const int row = w * 2 + rr;
        union { short8 v; short s[8]; } u;
        u.v = *(const short8*)(Xat + (size_t)(m0 + row) * 512 + ln * 8);
        float xv[8];
#pragma unroll
        for (int j = 0; j < 8; j++) xv[j] = bf2f(u.s[j]);
        float s = 0.f, q = 0.f;
#pragma unroll
        for (int j = 0; j < 8; j++) { s += xv[j]; q += xv[j] * xv[j]; }
#pragma unroll
        for (int off = 1; off < 64; off <<= 1) {
            s += __shfl_xor(s, off);
            q += __shfl_xor(q, off);
        }
        const float mean = s * (1.0f / DIM);
        const float var = q * (1.0f / DIM) - mean * mean;
        const float rstd = rsqrtf(var + 1e-5f);
        union { short8 v; short s[8]; } o;
#pragma unroll
        for (int j = 0; j < 8; j++)
            o.s[j] = f2bf((xv[j] - mean) * rstd * g0v.v[j] + b0v.v[j]);
        *(short8*)&As[row * 512 + ((ln ^ (row & 7)) * 8)] = o.v;
    }
    __syncthreads();

    // ---- phase 2: GEMM, 16 k-steps of K=32, barrier-free, B direct from L2 ----
    floatx4 acc[4];
#pragma unroll
    for (int j = 0; j < 4; j++) acc[j] = (floatx4)0.0f;
    const int pa = col & 7;                      // A chunk XOR (row&7 == col&7 for frag rows)
    const short* Bbase = WoT + (size_t)(w * 64 + col) * 512 + quad * 8;

#pragma unroll
    for (int t = 0; t < 16; t++) {
        const int qc = t * 4 + quad;
        const short8 af = *(const short8*)&As[col * 512 + ((qc ^ pa) * 8)];
#pragma unroll
        for (int j = 0; j < 4; j++) {
            const short8 bfj = *(const short8*)(Bbase + (size_t)j * 16 * 512 + t * 32);
            acc[j] = mfma16(af, bfj, acc[j]);
        }
    }

    // ---- phase 3: x = a + relu(acc+bo); LN1; fp32 out ----
    float xr[4][4];
    float sp[4], sq[4];
#pragma unroll
    for (int r = 0; r < 4; r++) { sp[r] = 0.f; sq[r] = 0.f; }
#pragma unroll
    for (int j = 0; j < 4; j++) {
        const int cj = w * 64 + j * 16 + col;
        const float bj = bo[cj];
        const int chunk = w * 8 + j * 2 + (col >> 3);
        const int ce = col & 7;
#pragma unroll
        for (int r = 0; r < 4; r++) {
            const int row = quad * 4 + r;
            const float y = fmaxf(acc[j][r] + bj, 0.0f);
            const float a = bf2f(As[row * 512 + ((chunk ^ (row & 7)) * 8) + ce]);
            const float xv = a + y;
            xr[j][r] = xv;
            sp[r] += xv;
            sq[r] += xv * xv;
        }
    }
#pragma unroll
    for (int r = 0; r < 4; r++) {
#pragma unroll
        for (int off = 1; off < 16; off <<= 1) {
            sp[r] += __shfl_xor(sp[r], off);
            sq[r] += __shfl_xor(sq[r], off);
        }
    }
    if (col == 0) {
#pragma unroll
        for (int r = 0; r < 4; r++) {
            const int row = quad * 4 + r;
            Ps[row][w][0] = sp[r];
            Ps[row][w][1] = sq[r];
        }
    }
    __syncthreads();
    if (tid < 16) {
        float s = 0.f, q = 0.f;
#pragma unroll
        for (int wv = 0; wv < 8; wv++) { s += Ps[tid][wv][0]; q += Ps[tid][wv][1]; }
        const float mean = s * (1.0f / DIM);
        const float var = q * (1.0f / DIM) - mean * mean;
        Ms[tid][0] = mean;
        Ms[tid][1] = rsqrtf(var + 1e-5f);
    }
    __syncthreads();
    float g1v[4], b1v[4];
#pragma unroll
    for (int j = 0; j < 4; j++) {
        const int cj = w * 64 + j * 16 + col;
        g1v[j] = g1[cj];
        b1v[j] = b1[cj];
    }
#pragma unroll
    for (int r = 0; r < 4; r++) {
        const int row = quad * 4 + r;
        const float mean = Ms[row][0];
        const float rstd = Ms[row][1];
#pragma unroll
        for (int j = 0; j < 4; j++) {
            const int cj = w * 64 + j * 16 + col;
            out[(size_t)(m0 + row) * 512 + cj] =
                (xr[j][r] - mean) * rstd * g1v[j] + b1v[j];
        }
    }
}

extern "C" void kernel_launch(void* const* d_in, const int* in_sizes, int n_in,
                              void* d_out, int out_size, void* d_ws, size_t ws_size,
                              hipStream_t stream) {
    const float* Q  = (const float*)d_in[0];
    const float* K  = (const float*)d_in[1];
    const float* Wq = (const float*)d_in[2];
    const float* bq = (const float*)d_in[3];
    const float* Wk = (const float*)d_in[4];
    const float* bk = (const float*)d_in[5];
    const float* Wv = (const float*)d_in[6];
    const float* bv = (const float*)d_in[7];
    const float* Wo = (const float*)d_in[8];
    const float* bo = (const float*)d_in[9];
    const float* g0 = (const float*)d_in[10];
    const float* b0 = (const float*)d_in[11];
    const float* g1 = (const float*)d_in[12];
    const float* b1 = (const float*)d_in[13];
    float* out = (float*)d_out;

    const size_t NE = (size_t)NTOK * DIM;
    char* p = (char*)d_ws;
    short* WqT  = (short*)p; p += 512 * 512 * 2;
    short* WkT  = (short*)p; p += 512 * 512 * 2;
    short* WvT  = (short*)p; p += 512 * 512 * 2;
    short* WoT  = (short*)p; p += 512 * 512 * 2;
    short* Qpb  = (short*)p; p += NE * 2;
    short* Kpb  = (short*)p; p += NE * 2;
    short* Vt   = (short*)p; p += NE * 2;   // [dv=512][tok=8192]
    short* Xat  = (short*)p; p += NE * 2;   // attn out + residual, bf16

    prep_kernel<<<256, 256, 0, stream>>>(Wq, Wk, Wv, Wo, WqT, WkT, WvT, WoT);
    proj_kernel<<<dim3(64, 12), 256, 0, stream>>>(Q, K, WqT, WkT, WvT,
                                                  bq, bk, bv, Qpb, Kpb, Vt);
    attn_kernel<<<512, 512, 0, stream>>>(Qpb, Kpb, Vt, Xat);
    gemm_final<<<512, 512, 0, stream>>>(Xat, WoT, bo, g0, b0, g1, b1, out);
}

// Round 8
// 182.788 us; speedup vs baseline: 1.0822x; 1.0822x over previous
//
#include <hip/hip_runtime.h>
#include <hip/hip_bf16.h>

#define DIM   512
#define NSEQ  1024
#define NB    8
#define NH    8
#define HD    64
#define NTOK  8192   // NB*NSEQ

typedef __attribute__((ext_vector_type(8))) short  short8;
typedef __attribute__((ext_vector_type(4))) short  short4v;
typedef __attribute__((ext_vector_type(4))) float  floatx4;
typedef __attribute__((ext_vector_type(4))) int    intx4;
typedef __attribute__((ext_vector_type(2))) int    intx2;
typedef __attribute__((ext_vector_type(8))) __bf16 bf16x8;

__device__ inline short f2bf(float x) {
    union { float f; unsigned u; } c; c.f = x;
    unsigned r = c.u + 0x7fffu + ((c.u >> 16) & 1u);
    return (short)(r >> 16);
}
__device__ inline float bf2f(short s) {
    union { unsigned u; float f; } c; c.u = ((unsigned)(unsigned short)s) << 16;
    return c.f;
}
// truncate-pack two fp32 -> two bf16 in one v_perm (used ONLY for attn P, where the
// softmax weights tolerate 1-ulp downward bias; do NOT use for GEMM inputs)
__device__ inline unsigned pkbf(float hi, float lo) {
    return __builtin_amdgcn_perm(
        __builtin_bit_cast(unsigned, hi), __builtin_bit_cast(unsigned, lo), 0x07060302u);
}
// round-to-nearest-even pack: 2 fp32 -> 2 bf16 (staging-phase only)
__device__ inline unsigned pkbf_rn(float hi, float lo) {
    unsigned uh = __builtin_bit_cast(unsigned, hi);
    unsigned ul = __builtin_bit_cast(unsigned, lo);
    uh += 0x7fffu + ((uh >> 16) & 1u);
    ul += 0x7fffu + ((ul >> 16) & 1u);
    return __builtin_amdgcn_perm(uh, ul, 0x07060302u);
}
// pack 8 fp32 (two float4) -> short8 of bf16, round-to-nearest
__device__ inline short8 pk8(float4 a, float4 b) {
    intx4 pk;
    pk.x = (int)pkbf_rn(a.y, a.x);
    pk.y = (int)pkbf_rn(a.w, a.z);
    pk.z = (int)pkbf_rn(b.y, b.x);
    pk.w = (int)pkbf_rn(b.w, b.z);
    return __builtin_bit_cast(short8, pk);
}
__device__ inline floatx4 mfma16(short8 a, short8 b, floatx4 c) {
    return __builtin_amdgcn_mfma_f32_16x16x32_bf16(
        __builtin_bit_cast(bf16x8, a), __builtin_bit_cast(bf16x8, b), c, 0, 0, 0);
}
__device__ inline floatx4 mfma_pv(short4v a, short4v b, floatx4 c) {
#if __has_builtin(__builtin_amdgcn_mfma_f32_16x16x16bf16_1k)
    return __builtin_amdgcn_mfma_f32_16x16x16bf16_1k(a, b, c, 0, 0, 0);
#else
    asm("v_mfma_f32_16x16x16_bf16 %0, %1, %2, %0" : "+v"(c) : "v"(a), "v"(b));
    return c;
#endif
}
__device__ inline void gld_lds16(const void* g, void* l) {
    __builtin_amdgcn_global_load_lds(
        (__attribute__((address_space(1))) void*)(g),
        (__attribute__((address_space(3))) void*)(l), 16, 0, 0);
}

// ---------------- prep: tiled W transpose only (256 blocks) ----------------
__global__ __launch_bounds__(256) void prep_kernel(
        const float* __restrict__ Wq, const float* __restrict__ Wk,
        const float* __restrict__ Wv, const float* __restrict__ Wo,
        short* __restrict__ WqT, short* __restrict__ WkT,
        short* __restrict__ WvT, short* __restrict__ WoT) {
    const int tid = threadIdx.x;
    __shared__ short Ts[64 * 65];
    const int b = blockIdx.x;
    const int wsel = b >> 6, tile = b & 63;
    const int tr = (tile >> 3) * 64;                // k base
    const int tc = (tile & 7) * 64;                 // n base
    const float* src = (wsel == 0) ? Wq : (wsel == 1) ? Wk : (wsel == 2) ? Wv : Wo;
    short* dst       = (wsel == 0) ? WqT : (wsel == 1) ? WkT : (wsel == 2) ? WvT : WoT;
#pragma unroll
    for (int i = 0; i < 16; i++) {
        const int idx = i * 256 + tid;              // over 64x64
        const int r = idx >> 6, c = idx & 63;       // coalesced read
        Ts[c * 65 + r] = f2bf(src[(size_t)(tr + r) * 512 + tc + c]);
    }
    __syncthreads();
#pragma unroll
    for (int i = 0; i < 16; i++) {
        const int idx = i * 256 + tid;
        const int n = idx >> 6, k = idx & 63;       // coalesced write
        dst[(size_t)(tc + n) * 512 + tr + k] = Ts[n * 65 + k];
    }
}

// ---------------- fused QKV projection GEMM: n-tile 256, T14 reg-staged ----------------------
// R7 post-mortem: proj is STAGED-BYTES-bound (288 MB @ ~6.6 TB/s effective = 45 us; every
// structural variant at same bytes landed 44-48 us). This version halves A re-reads by
// widening the n-tile to 256 (8 waves x same 64x64 wave tile): staged = 192 MB (-33%).
// grid (64, 6): x = m-block, y: sel = y>>1 {0:Q->Qpb, 1:K->Kpb, 2:K->Vt}, n0 = (y&1)*256.
__global__ __launch_bounds__(512) void proj_kernel(
        const float* __restrict__ Qf, const float* __restrict__ Kf,
        const short* __restrict__ WqT, const short* __restrict__ WkT,
        const short* __restrict__ WvT,
        const float* __restrict__ bq, const float* __restrict__ bk,
        const float* __restrict__ bv,
        short* __restrict__ Qpb, short* __restrict__ Kpb,
        short* __restrict__ Vt) {
    __shared__ __attribute__((aligned(16))) char smem[49152]; // As 16K + Bs 32K; epilogue reuses
    short* As = (short*)smem;                 // 128 x 64 bf16
    short* Bs = (short*)(smem + 16384);       // 256 x 64 bf16
    const int tid = threadIdx.x;
    const int w = tid >> 6, ln = tid & 63;
    const int quad = ln >> 4, col = ln & 15;
    const int nb = blockIdx.y;
    const int sel = nb >> 1;
    const int n0 = (nb & 1) * 256;
    const int m0 = blockIdx.x * 128;
    const int wr = w >> 2, wc = w & 3;        // wave tile: rows [wr*64,+64), cols [n0+wc*64,+64)
    const float* Af   = (sel == 0) ? Qf : Kf;
    const short* BT   = (sel == 0) ? WqT : (sel == 1) ? WkT : WvT;
    const float* bias = (sel == 0) ? bq : (sel == 1) ? bk : bv;

    floatx4 acc[4][4];
#pragma unroll
    for (int i = 0; i < 4; i++)
#pragma unroll
        for (int j = 0; j < 4; j++) acc[i][j] = (floatx4)0.0f;

    // staging slots (512 threads): A = 1024 chunks of 8 fp32; B = 2048 chunks of 8 bf16;
    // slot -> r = slot>>3, c = (slot&7)^(r&7)
    const float* Ag[2]; int lofA[2];
#pragma unroll
    for (int i = 0; i < 2; i++) {
        const int slot = i * 512 + tid;
        const int r = slot >> 3;
        const int c = (slot & 7) ^ (r & 7);
        Ag[i] = Af + (size_t)(m0 + r) * 512 + c * 8;   // 32B fp32 per chunk
        lofA[i] = slot * 8;
    }
    const short* Bg[4]; int lofB[4];
#pragma unroll
    for (int i = 0; i < 4; i++) {
        const int slot = i * 512 + tid;
        const int r = slot >> 3;
        const int c = (slot & 7) ^ (r & 7);
        Bg[i] = BT + (size_t)(n0 + r) * 512 + c * 8;   // 16B bf16 per chunk
        lofB[i] = slot * 8;
    }

    float4 raf[2][2]; short8 rbv[4];
#pragma unroll
    for (int i = 0; i < 2; i++) {
        raf[i][0] = *(const float4*)(Ag[i]);
        raf[i][1] = *(const float4*)(Ag[i] + 4);
    }
#pragma unroll
    for (int i = 0; i < 4; i++) rbv[i] = *(const short8*)(Bg[i]);
#pragma unroll
    for (int i = 0; i < 2; i++) *(short8*)&As[lofA[i]] = pk8(raf[i][0], raf[i][1]);
#pragma unroll
    for (int i = 0; i < 4; i++) *(short8*)&Bs[lofB[i]] = rbv[i];
    __syncthreads();

    for (int t = 0; t < 8; t++) {
        if (t < 7) {
            const int kk = (t + 1) * 64;
#pragma unroll
            for (int i = 0; i < 2; i++) {
                raf[i][0] = *(const float4*)(Ag[i] + kk);
                raf[i][1] = *(const float4*)(Ag[i] + kk + 4);
            }
#pragma unroll
            for (int i = 0; i < 4; i++) rbv[i] = *(const short8*)(Bg[i] + kk);
        }
#pragma unroll
        for (int s = 0; s < 2; s++) {
            short8 af[4], bfr[4];
#pragma unroll
            for (int i = 0; i < 4; i++) {
                const int row = wr * 64 + i * 16 + col;      // row&7 == col&7
                const int cs = (s * 4 + quad) ^ (col & 7);
                af[i] = *(const short8*)&As[row * 64 + cs * 8];
            }
#pragma unroll
            for (int j = 0; j < 4; j++) {
                const int row = wc * 64 + j * 16 + col;      // row&7 == col&7
                const int cs = (s * 4 + quad) ^ (col & 7);
                bfr[j] = *(const short8*)&Bs[row * 64 + cs * 8];
            }
#pragma unroll
            for (int i = 0; i < 4; i++)
#pragma unroll
                for (int j = 0; j < 4; j++)
                    acc[i][j] = mfma16(af[i], bfr[j], acc[i][j]);
        }
        __syncthreads();                 // all waves done reading the buffer
        if (t < 7) {
#pragma unroll
            for (int i = 0; i < 2; i++)
                *(short8*)&As[lofA[i]] = pk8(raf[i][0], raf[i][1]); // vmcnt wait lands here
#pragma unroll
            for (int i = 0; i < 4; i++) *(short8*)&Bs[lofB[i]] = rbv[i];
        }
        __syncthreads();                 // buffer ready for next step
    }

    if (sel < 2) {
        // coalesced epilogue in 2 wave-rounds (4 waves each share the 36.9KB Es region)
        short* C = (sel == 0) ? Qpb : Kpb;
        const int lr = ln >> 3, lc = (ln & 7) * 8;
#pragma unroll
        for (int round = 0; round < 2; round++) {
            __syncthreads();
            if (wr == round) {
                short* Es = (short*)smem + wc * (64 * 72);   // wave-private 64x72
#pragma unroll
                for (int j = 0; j < 4; j++) {
                    const float bj = bias[n0 + wc * 64 + j * 16 + col];
#pragma unroll
                    for (int i = 0; i < 4; i++)
#pragma unroll
                        for (int r = 0; r < 4; r++)
                            Es[(i * 16 + quad * 4 + r) * 72 + j * 16 + col] =
                                f2bf(acc[i][j][r] + bj);
                }
                // intra-wave RAW ordering suffices
#pragma unroll
                for (int u = 0; u < 8; u++) {
                    const short8 v = *(const short8*)&Es[(u * 8 + lr) * 72 + lc];
                    *(short8*)(C + (size_t)(m0 + wr * 64 + u * 8 + lr) * 512
                                 + n0 + wc * 64 + lc) = v;
                }
            }
        }
    } else {
        // transposed epilogue: Vt[dv][tok]; 4 column-rounds of 64 dv x 128 tok through LDS
        short* Ts = (short*)smem;                    // 64 x 136 = 17408 B
        const int dvl = tid >> 3;
        const int tch = (tid & 7) * 16;
#pragma unroll
        for (int hc = 0; hc < 4; hc++) {
            __syncthreads();
            if (wc == hc) {                          // 2 waves (wr=0,1) cover tok halves
#pragma unroll
                for (int j = 0; j < 4; j++) {
                    const float bj = bias[n0 + hc * 64 + j * 16 + col];
#pragma unroll
                    for (int i = 0; i < 4; i++)
#pragma unroll
                        for (int r = 0; r < 4; r++)
                            Ts[(j * 16 + col) * 136 + wr * 64 + i * 16 + quad * 4 + r] =
                                f2bf(acc[i][j][r] + bj);
                }
            }
            __syncthreads();
#pragma unroll
            for (int u = 0; u < 2; u++)
                *(intx4*)(Vt + (size_t)(n0 + hc * 64 + dvl) * NTOK + m0 + tch + u * 8) =
                    *(const intx4*)&Ts[dvl * 136 + tch + u * 8];
        }
    }
}

// ---------------- fused flash attention + residual (R9 structure) ----------------
__global__ __launch_bounds__(512) void attn_kernel(
        const short* __restrict__ Qp, const short* __restrict__ Kp,
        const short* __restrict__ Vt, short* __restrict__ Xo) {
    __shared__ __attribute__((aligned(16))) short Ks[2][128 * 64];
    __shared__ __attribute__((aligned(16))) short Vs[2][64 * 128];
    const int tid = threadIdx.x;
    const int w = tid >> 6, ln = tid & 63;
    const int quad = ln >> 4, col = ln & 15;
    const int gid = blockIdx.x;
    const int h = gid & 7;                  // XCD pin: one head per XCD
    const int rest = gid >> 3;              // 0..63
    const int b = rest >> 3;                // 0..7
    const int qt = rest & 7;                // 0..7
    const int q0 = qt * 128 + w * 16;
    const size_t baseQ = (size_t)b * NSEQ * DIM + (size_t)h * HD;
    const size_t baseV = (size_t)h * HD * NTOK + (size_t)b * NSEQ;
    const float sc = 1.44269504089f / 22.6274169979f;   // log2e / sqrt(512)

    const int ks0 = tid, ks1 = 512 + tid;
    const int kr0 = ks0 >> 3, kc0 = (ks0 & 7) ^ (kr0 & 7);
    const int kr1 = ks1 >> 3, kc1 = (ks1 & 7) ^ (kr1 & 7);
    const int vr0 = ks0 >> 4, vc0 = (ks0 & 15) ^ (vr0 & 15);
    const int vr1 = ks1 >> 4, vc1 = (ks1 & 15) ^ (vr1 & 15);
    const short* kp0 = Kp + baseQ + (size_t)kr0 * DIM + kc0 * 8;
    const short* kp1 = Kp + baseQ + (size_t)kr1 * DIM + kc1 * 8;
    const short* vp0 = Vt + baseV + (size_t)vr0 * NTOK + vc0 * 8;
    const short* vp1 = Vt + baseV + (size_t)vr1 * NTOK + vc1 * 8;
    const int ldsl0 = (w * 64) * 8;
    const int ldsl1 = (512 + w * 64) * 8;

    short8 qa[2];
#pragma unroll
    for (int s = 0; s < 2; s++) {
        short8 raw = *(const short8*)(Qp + baseQ + (size_t)(q0 + col) * DIM + s * 32 + quad * 8);
        short8 sq;
#pragma unroll
        for (int j = 0; j < 8; j++) sq[j] = f2bf(bf2f(raw[j]) * sc);
        qa[s] = sq;
    }

    floatx4 oacc[4];
#pragma unroll
    for (int dt = 0; dt < 4; dt++) oacc[dt] = (floatx4)0.0f;
    float lp = 0.0f;

    gld_lds16(kp0, &Ks[0][ldsl0]);
    gld_lds16(kp1, &Ks[0][ldsl1]);
    gld_lds16(vp0, &Vs[0][ldsl0]);
    gld_lds16(vp1, &Vs[0][ldsl1]);
    __syncthreads();

    for (int t = 0; t < 8; t++) {
        const int cur = t & 1;
        if (t < 7) {
            const int kn = (t + 1) * 128;    // K advances by rows, V by cols
            const int nxt = cur ^ 1;
            gld_lds16(kp0 + (size_t)kn * DIM, &Ks[nxt][ldsl0]);
            gld_lds16(kp1 + (size_t)kn * DIM, &Ks[nxt][ldsl1]);
            gld_lds16(vp0 + kn, &Vs[nxt][ldsl0]);
            gld_lds16(vp1 + kn, &Vs[nxt][ldsl1]);
        }
        const short* Kc = Ks[cur];
        const short* Vc = Vs[cur];
#pragma unroll
        for (int nt = 0; nt < 8; nt++) {
            floatx4 z = (floatx4)0.0f;
#pragma unroll
            for (int s = 0; s < 2; s++) {
                const int cs = (s * 4 + quad) ^ (col & 7);
                const short8 kf = *(const short8*)&Kc[(nt * 16 + col) * 64 + cs * 8];
                z = mfma16(kf, qa[s], z);           // S^T tile
            }
            const float p0 = exp2f(z[0]), p1 = exp2f(z[1]);
            const float p2 = exp2f(z[2]), p3 = exp2f(z[3]);
            lp += (p0 + p1) + (p2 + p3);
            intx2 pd; pd.x = (int)pkbf(p1, p0); pd.y = (int)pkbf(p3, p2);
            const short4v pf = __builtin_bit_cast(short4v, pd);
#pragma unroll
            for (int dt = 0; dt < 4; dt++) {
                const int cs = (nt * 2 + (quad >> 1)) ^ col;
                const short4v vf = *(const short4v*)&Vc[(dt * 16 + col) * 128 + cs * 8 + (quad & 1) * 4];
                oacc[dt] = mfma_pv(pf, vf, oacc[dt]);
            }
        }
        __syncthreads();
    }

    lp += __shfl_xor(lp, 16);
    lp += __shfl_xor(lp, 32);
    float linv[4];
#pragma unroll
    for (int r = 0; r < 4; r++) linv[r] = 1.0f / __shfl(lp, quad * 4 + r);

#pragma unroll
    for (int dt = 0; dt < 4; dt++) {
#pragma unroll
        for (int r = 0; r < 4; r++) {
            const int q = q0 + quad * 4 + r;
            const size_t off = baseQ + (size_t)q * DIM + dt * 16 + col;
            Xo[off] = f2bf(oacc[dt][r] * linv[r] + bf2f(Qp[off]));
        }
    }
}

// ---------------- fused LN0 + out-proj GEMM + relu + residual + LN1, fp32 out ----------------
// grid 256 blocks x 512 threads; M=32 rows/block, full N=512 (R5 version — M=16 regressed:
// B traffic/block is constant, so more blocks = more L2 traffic at lower arith intensity).
__global__ __launch_bounds__(512) void gemm_final(
        const short* __restrict__ Xat, const short* __restrict__ WoT,
        const float* __restrict__ bo,
        const float* __restrict__ g0, const float* __restrict__ b0,
        const float* __restrict__ g1, const float* __restrict__ b1,
        float* __restrict__ out) {
    __shared__ __attribute__((aligned(16))) short As[32 * 512];      // 32 KB LN0'd A
    __shared__ float Ps[32][8][2];                                   // per-row per-wave partials
    __shared__ float Ms[32][2];                                      // mean, rstd per row
    const int tid = threadIdx.x;
    const int w = tid >> 6, ln = tid & 63;
    const int quad = ln >> 4, col = ln & 15;
    const int m0 = blockIdx.x * 32;

    // ---- phase 1: LN0 over this block's 32 rows (4 per wave) ----
    union { float4 f[2]; float v[8]; } g0v, b0v;
    g0v.f[0] = *(const float4*)(g0 + ln * 8); g0v.f[1] = *(const float4*)(g0 + ln * 8 + 4);
    b0v.f[0] = *(const float4*)(b0 + ln * 8); b0v.f[1] = *(const float4*)(b0 + ln * 8 + 4);
#pragma unroll
    for (int rr = 0; rr < 4; rr++) {
        const int row = w * 4 + rr;
        union { short8 v; short s[8]; } u;
        u.v = *(const short8*)(Xat + (size_t)(m0 + row) * 512 + ln * 8);
        float xv[8];
#pragma unroll
        for (int j = 0; j < 8; j++) xv[j] = bf2f(u.s[j]);
        float s = 0.f, q = 0.f;
#pragma unroll
        for (int j = 0; j < 8; j++) { s += xv[j]; q += xv[j] * xv[j]; }
#pragma unroll
        for (int off = 1; off < 64; off <<= 1) {
            s += __shfl_xor(s, off);
            q += __shfl_xor(q, off);
        }
        const float mean = s * (1.0f / DIM);
        const float var = q * (1.0f / DIM) - mean * mean;
        const float rstd = rsqrtf(var + 1e-5f);
        union { short8 v; short s[8]; } o;
#pragma unroll
        for (int j = 0; j < 8; j++)
            o.s[j] = f2bf((xv[j] - mean) * rstd * g0v.v[j] + b0v.v[j]);
        *(short8*)&As[row * 512 + ((ln ^ (row & 7)) * 8)] = o.v;
    }
    __syncthreads();

    // ---- phase 2: GEMM, 16 k-steps of K=32, barrier-free, B direct from L2 ----
    floatx4 acc[2][4];
#pragma unroll
    for (int i = 0; i < 2; i++)
#pragma unroll
        for (int j = 0; j < 4; j++) acc[i][j] = (floatx4)0.0f;
    const int pa = col & 7;                      // A chunk XOR (row&7 == col&7 for frag rows)
    const short* Bbase = WoT + (size_t)(w * 64 + col) * 512 + quad * 8;

#pragma unroll 4
    for (int t = 0; t < 16; t++) {
        const int qc = t * 4 + quad;
        const short8 af0 = *(const short8*)&As[col * 512 + ((qc ^ pa) * 8)];
        const short8 af1 = *(const short8*)&As[(16 + col) * 512 + ((qc ^ pa) * 8)];
#pragma unroll
        for (int j = 0; j < 4; j++) {
            const short8 bfj = *(const short8*)(Bbase + (size_t)j * 16 * 512 + t * 32);
            acc[0][j] = mfma16(af0, bfj, acc[0][j]);
            acc[1][j] = mfma16(af1, bfj, acc[1][j]);
        }
    }

    // ---- phase 3: x = a + relu(acc+bo); LN1; fp32 out ----
    float xr[2][4][4];
    float sp[2][4], sq[2][4];
#pragma unroll
    for (int i = 0; i < 2; i++)
#pragma unroll
        for (int r = 0; r < 4; r++) { sp[i][r] = 0.f; sq[i][r] = 0.f; }
#pragma unroll
    for (int j = 0; j < 4; j++) {
        const int cj = w * 64 + j * 16 + col;
        const float bj = bo[cj];
        const int chunk = w * 8 + j * 2 + (col >> 3);
        const int ce = col & 7;
#pragma unroll
        for (int i = 0; i < 2; i++)
#pragma unroll
            for (int r = 0; r < 4; r++) {
                const int row = i * 16 + quad * 4 + r;
                const float y = fmaxf(acc[i][j][r] + bj, 0.0f);
                const float a = bf2f(As[row * 512 + ((chunk ^ (row & 7)) * 8) + ce]);
                const float xv = a + y;
                xr[i][j][r] = xv;
                sp[i][r] += xv;
                sq[i][r] += xv * xv;
            }
    }
#pragma unroll
    for (int i = 0; i < 2; i++)
#pragma unroll
        for (int r = 0; r < 4; r++) {
#pragma unroll
            for (int off = 1; off < 16; off <<= 1) {
                sp[i][r] += __shfl_xor(sp[i][r], off);
                sq[i][r] += __shfl_xor(sq[i][r], off);
            }
        }
    if (col == 0) {
#pragma unroll
        for (int i = 0; i < 2; i++)
#pragma unroll
            for (int r = 0; r < 4; r++) {
                const int row = i * 16 + quad * 4 + r;
                Ps[row][w][0] = sp[i][r];
                Ps[row][w][1] = sq[i][r];
            }
    }
    __syncthreads();
    if (tid < 32) {
        float s = 0.f, q = 0.f;
#pragma unroll
        for (int wv = 0; wv < 8; wv++) { s += Ps[tid][wv][0]; q += Ps[tid][wv][1]; }
        const float mean = s * (1.0f / DIM);
        const float var = q * (1.0f / DIM) - mean * mean;
        Ms[tid][0] = mean;
        Ms[tid][1] = rsqrtf(var + 1e-5f);
    }
    __syncthreads();
    float g1v[4], b1v[4];
#pragma unroll
    for (int j = 0; j < 4; j++) {
        const int cj = w * 64 + j * 16 + col;
        g1v[j] = g1[cj];
        b1v[j] = b1[cj];
    }
#pragma unroll
    for (int i = 0; i < 2; i++)
#pragma unroll
        for (int r = 0; r < 4; r++) {
            const int row = i * 16 + quad * 4 + r;
            const float mean = Ms[row][0];
            const float rstd = Ms[row][1];
#pragma unroll
            for (int j = 0; j < 4; j++) {
                const int cj = w * 64 + j * 16 + col;
                out[(size_t)(m0 + row) * 512 + cj] =
                    (xr[i][j][r] - mean) * rstd * g1v[j] + b1v[j];
            }
        }
}

extern "C" void kernel_launch(void* const* d_in, const int* in_sizes, int n_in,
                              void* d_out, int out_size, void* d_ws, size_t ws_size,
                              hipStream_t stream) {
    const float* Q  = (const float*)d_in[0];
    const float* K  = (const float*)d_in[1];
    const float* Wq = (const float*)d_in[2];
    const float* bq = (const float*)d_in[3];
    const float* Wk = (const float*)d_in[4];
    const float* bk = (const float*)d_in[5];
    const float* Wv = (const float*)d_in[6];
    const float* bv = (const float*)d_in[7];
    const float* Wo = (const float*)d_in[8];
    const float* bo = (const float*)d_in[9];
    const float* g0 = (const float*)d_in[10];
    const float* b0 = (const float*)d_in[11];
    const float* g1 = (const float*)d_in[12];
    const float* b1 = (const float*)d_in[13];
    float* out = (float*)d_out;

    const size_t NE = (size_t)NTOK * DIM;
    char* p = (char*)d_ws;
    short* WqT  = (short*)p; p += 512 * 512 * 2;
    short* WkT  = (short*)p; p += 512 * 512 * 2;
    short* WvT  = (short*)p; p += 512 * 512 * 2;
    short* WoT  = (short*)p; p += 512 * 512 * 2;
    short* Qpb  = (short*)p; p += NE * 2;
    short* Kpb  = (short*)p; p += NE * 2;
    short* Vt   = (short*)p; p += NE * 2;   // [dv=512][tok=8192]
    short* Xat  = (short*)p; p += NE * 2;   // attn out + residual, bf16

    prep_kernel<<<256, 256, 0, stream>>>(Wq, Wk, Wv, Wo, WqT, WkT, WvT, WoT);
    proj_kernel<<<dim3(64, 6), 512, 0, stream>>>(Q, K, WqT, WkT, WvT,
                                                 bq, bk, bv, Qpb, Kpb, Vt);
    attn_kernel<<<512, 512, 0, stream>>>(Qpb, Kpb, Vt, Xat);
    gemm_final<<<256, 512, 0, stream>>>(Xat, WoT, bo, g0, b0, g1, b1, out);
}